// Round 3
// baseline (59242.206 us; speedup 1.0000x reference)
//
#include <hip/hip_runtime.h>
#include <stdint.h>

#define NBLK 256
#define NTHR 512

typedef __attribute__((ext_vector_type(8))) short short8;
typedef __attribute__((ext_vector_type(4))) float float4_;

// workspace layout (bytes)
#define WS_FLG   0          // 256 * u32 arrival flags = 1024
#define WS_HDN   1024       // 512*128 ushort (bf16)   = 131072
#define WS_KP    132096     // 4*512*64 float          = 524288
#define WS_SIGT  656384     // 528*512 float           = 1081344
// total = 1737728 bytes

#define LOADC(p)    __hip_atomic_load((p),  __ATOMIC_RELAXED, __HIP_MEMORY_SCOPE_SYSTEM)
#define STOREC(p,v) __hip_atomic_store((p), (v), __ATOMIC_RELAXED, __HIP_MEMORY_SCOPE_SYSTEM)

__device__ __forceinline__ unsigned short f2bf(float x) {
  union { float f; unsigned u; } v; v.f = x;
  return (unsigned short)((v.u + 0x7fffu + ((v.u >> 16) & 1u)) >> 16);
}

__device__ __forceinline__ float fast_exp(float x) {  // e^x ; saturates cleanly
  return __builtin_amdgcn_exp2f(x * 1.4426950408889634f);
}

__device__ __forceinline__ float fast_tanh(float x) {
  // e^(2x): overflow->inf => rcp->0 => tanh=1 ; underflow->0 => tanh=-1. No clamps needed.
  float e = __builtin_amdgcn_exp2f(x * 2.8853900817779268f);
  return fmaf(-2.0f, __builtin_amdgcn_rcpf(e + 1.0f), 1.0f);
}

__device__ __forceinline__ float fast_silu(float x) {
  float e = fast_exp(-x);
  return x * __builtin_amdgcn_rcpf(1.0f + e);
}

// Distributed-flag grid barrier: zero atomic contention.
// Arrival: each block stores target into its own flag word (system scope).
// Completion: wave0 of every block polls all 256 flags (4 loads/lane + ballot).
// Targets are monotone increasing across the whole kernel -> no reset, no ABA.
// __syncthreads() at entry drains vmcnt(0) for every wave, so all prior
// system-scope data stores have reached the coherence point before the flag.
__device__ __forceinline__ void gridbar(unsigned* F, unsigned target, int g) {
  __syncthreads();
  const int tid = threadIdx.x;
  if (tid < 64) {
    if (tid == 0) {
      asm volatile("s_waitcnt vmcnt(0)" ::: "memory");
      STOREC(&F[g], target);
    }
    bool done;
    do {
      unsigned a = LOADC(&F[tid]);
      unsigned b = LOADC(&F[tid + 64]);
      unsigned c = LOADC(&F[tid + 128]);
      unsigned d = LOADC(&F[tid + 192]);
      done = (a >= target) & (b >= target) & (c >= target) & (d >= target);
    } while (!__all(done));
  }
  __syncthreads();
}

__global__ void __launch_bounds__(NTHR, 2)
rde_kernel(const float* __restrict__ ts, const float* __restrict__ logsig,
           const float* __restrict__ x0, const float* __restrict__ intervals,
           const float* __restrict__ w0, const float* __restrict__ b0,
           const float* __restrict__ w1, const float* __restrict__ b1,
           const float* __restrict__ w2, const float* __restrict__ b2,
           const float* __restrict__ w3, const float* __restrict__ b3,
           const float* __restrict__ l1w, const float* __restrict__ l1b,
           const float* __restrict__ l2w, const float* __restrict__ l2b,
           float* out, unsigned char* ws) {
  const int tid = threadIdx.x;
  const int g   = blockIdx.x;
  const int h   = g >> 2;          // owned output-head (0..63)
  const int q   = g & 3;           // quarter of the 528 l-range
  const int ntiles = (q == 3) ? 9 : 8;   // 16-wide n-tiles (33 per h total)
  const int l0g = q << 7;          // l offset within h's 528

  unsigned long long* H64 = (unsigned long long*)(ws + WS_HDN);
  float* KP  = (float*)(ws + WS_KP);
  float* SGT = (float*)(ws + WS_SIGT);
  unsigned* FLG = (unsigned*)(ws + WS_FLG);

  __shared__ __attribute__((aligned(16))) unsigned short W3lds[18432]; // 36.9 KB
  __shared__ float b3lds[144];
  __shared__ float intv[64];
  __shared__ float yLDS[2][64];
  __shared__ float kh[6][2][64];
  __shared__ float yst[2][64];
  __shared__ float hbA[2][128];
  __shared__ float hbB[2][128];
  __shared__ __attribute__((aligned(8))) unsigned short hdnS[2][128];
  __shared__ float tsc[16][513];   // transpose scratch (32.8 KB)
  __shared__ int   sidx;

  // ---------------- init ----------------
  if (tid < 64) intv[tid] = intervals[tid];
  {
    const int tot = ntiles * 16 * 128;
    for (int e = tid; e < tot; e += NTHR) {
      int k  = e & 127;
      int nc = e >> 7;
      float v = w3[(size_t)(h * 528 + l0g + nc) * 128 + k];
      int col = nc & 15, nt = nc >> 4;
      int kb = k >> 5, qd = (k >> 3) & 3, j = k & 7;
      // layout: lane reads contiguous 16B at (nt*4+kb)*512 + lane*8
      W3lds[(nt * 4 + kb) * 512 + qd * 128 + col * 8 + j] = f2bf(v);
    }
    for (int e = tid; e < ntiles * 16; e += NTHR)
      b3lds[e] = b3[h * 528 + l0g + e];
  }
  if (tid < 128) {  // y0 = x0 @ l1_w.T + l1_b for own 2 rows
    int row = tid >> 6, hh = tid & 63;
    float acc = l1b[hh];
    const float* xr = x0 + (size_t)(2 * g + row) * 32;
    const float* wr = l1w + hh * 32;
    #pragma unroll
    for (int d = 0; d < 32; ++d) acc = fmaf(xr[d], wr[d], acc);
    yLDS[row][hh] = acc;
  }
  const float t0v = ts[0];
  const float dtv = (ts[128] - t0v) * (1.0f / 256.0f);
  int last_idx = -1;
  __syncthreads();

  // ---------------- 1536 sequential RK stages ----------------
  for (int sg = 0; sg < 1536; ++sg) {
    const int s_in  = sg % 6;
    const int stepi = sg / 6;

    // ---- P1: consume k of previous stage, RK combine, MLP -> hdn ----
    if (tid < 128) {
      const int row = tid >> 6, hh = tid & 63;
      if (sg > 0) {
        const int b = 2 * g + row;
        const int pi = (s_in == 0) ? 5 : (s_in - 1);
        float s = LOADC(&KP[(size_t)(0 * 512 + b) * 64 + hh])
                + LOADC(&KP[(size_t)(1 * 512 + b) * 64 + hh])
                + LOADC(&KP[(size_t)(2 * 512 + b) * 64 + hh])
                + LOADC(&KP[(size_t)(3 * 512 + b) * 64 + hh]);
        kh[pi][row][hh] = s;
      }
      float yv = yLDS[row][hh];
      if (s_in == 0) {
        if (sg > 0) {
          float comb = 0.09646076681806523f  * kh[0][row][hh]
                     + 0.01f                 * kh[1][row][hh]
                     + 0.4798896504144996f   * kh[2][row][hh]
                     + 1.379008574103742f    * kh[3][row][hh]
                     + (-3.290069515436081f) * kh[4][row][hh]
                     + 2.324710524099774f    * kh[5][row][hh];
          yv += dtv * comb;
          yLDS[row][hh] = yv;
        }
        yst[row][hh] = yv;
      } else {
        float comb;
        switch (s_in) {
          case 1: comb = 0.161f * kh[0][row][hh]; break;
          case 2: comb = -0.008480655492356989f * kh[0][row][hh]
                        + 0.335480655492357f    * kh[1][row][hh]; break;
          case 3: comb = 2.8971530571054935f  * kh[0][row][hh]
                        - 6.359448489975075f  * kh[1][row][hh]
                        + 4.3622954328695815f * kh[2][row][hh]; break;
          case 4: comb = 5.325864828439257f    * kh[0][row][hh]
                        - 11.748883564062828f  * kh[1][row][hh]
                        + 7.4955393428898365f  * kh[2][row][hh]
                        - 0.09249506636175525f * kh[3][row][hh]; break;
          default: comb = 5.86145544294642f      * kh[0][row][hh]
                        - 12.92096931784711f     * kh[1][row][hh]
                        + 8.159367898576159f     * kh[2][row][hh]
                        - 0.071584973281401f     * kh[3][row][hh]
                        - 0.028269050394068383f  * kh[4][row][hh]; break;
        }
        yst[row][hh] = yv + dtv * comb;
      }
    }
    // stage time + searchsorted idx (wave0 ballot)
    {
      float t_s = __fadd_rn(t0v, __fmul_rn((float)stepi, dtv));
      if (s_in != 0) {
        float c = (s_in == 1) ? 0.161f : (s_in == 2) ? 0.327f : (s_in == 3) ? 0.9f
                : (s_in == 4) ? 0.9800255409045097f : 1.0f;
        t_s = __fadd_rn(t_s, __fmul_rn(c, dtv));
      }
      if (tid < 64) {
        unsigned long long m = __ballot(intv[tid] < t_s);
        if (tid == 0) sidx = (int)__popcll(m);
      }
    }
    __syncthreads();
    const int idx = sidx;
    // idx is monotone non-decreasing over stages -> <=65 rebuilds of sigT
    const bool rebuild = (idx != last_idx);
    if (rebuild) {
      last_idx = idx;
      if (g < 33) {  // blocks 0..32 transpose one 16-wide l-stripe each
        const int l0t = g * 16;
        #pragma unroll 1
        for (int it = 0; it < 16; ++it) {
          int li = tid & 15, b = (tid >> 4) + 32 * it;
          tsc[li][b] = logsig[((size_t)b * 65 + idx) * 529 + 1 + l0t + li];
        }
        __syncthreads();
        #pragma unroll 1
        for (int it = 0; it < 16; ++it) {
          int li = tid >> 5, b = (tid & 31) + 32 * it;
          STOREC(&SGT[(size_t)(l0t + li) * 512 + b], tsc[li][b]);
        }
      }
    }
    // MLP (2 rows, 256 threads): silu(y@w0^T) -> silu(@w1^T) -> silu(@w2^T) -> hdn bf16
    if (tid < 256) {
      const int row = tid >> 7, j = tid & 127;
      float acc = b0[j];
      const float4_* wr = (const float4_*)(w0 + (size_t)j * 64);
      #pragma unroll
      for (int i4 = 0; i4 < 16; ++i4) {
        float4_ wv = wr[i4];
        acc = fmaf(yst[row][4*i4+0], wv[0], acc);
        acc = fmaf(yst[row][4*i4+1], wv[1], acc);
        acc = fmaf(yst[row][4*i4+2], wv[2], acc);
        acc = fmaf(yst[row][4*i4+3], wv[3], acc);
      }
      hbA[row][j] = fast_silu(acc);
    }
    __syncthreads();
    if (tid < 256) {
      const int row = tid >> 7, j = tid & 127;
      float acc = b1[j];
      const float4_* wr = (const float4_*)(w1 + (size_t)j * 128);
      #pragma unroll
      for (int i4 = 0; i4 < 32; ++i4) {
        float4_ wv = wr[i4];
        acc = fmaf(hbA[row][4*i4+0], wv[0], acc);
        acc = fmaf(hbA[row][4*i4+1], wv[1], acc);
        acc = fmaf(hbA[row][4*i4+2], wv[2], acc);
        acc = fmaf(hbA[row][4*i4+3], wv[3], acc);
      }
      hbB[row][j] = fast_silu(acc);
    }
    __syncthreads();
    if (tid < 256) {
      const int row = tid >> 7, j = tid & 127;
      float acc = b2[j];
      const float4_* wr = (const float4_*)(w2 + (size_t)j * 128);
      #pragma unroll
      for (int i4 = 0; i4 < 32; ++i4) {
        float4_ wv = wr[i4];
        acc = fmaf(hbB[row][4*i4+0], wv[0], acc);
        acc = fmaf(hbB[row][4*i4+1], wv[1], acc);
        acc = fmaf(hbB[row][4*i4+2], wv[2], acc);
        acc = fmaf(hbB[row][4*i4+3], wv[3], acc);
      }
      hdnS[row][j] = f2bf(fast_silu(acc));
    }
    __syncthreads();
    if (tid < 64) {  // pack 2 rows (512 B) as 64 coherent 8B stores
      const unsigned long long* s64 = (const unsigned long long*)&hdnS[0][0];
      STOREC(&H64[(size_t)g * 64 + tid], s64[tid]);
    }
    gridbar(FLG, 2u * (unsigned)sg + 1u, g);
    if (rebuild) __builtin_amdgcn_fence(__ATOMIC_ACQUIRE, "agent"); // invalidate stale SGT lines (rare)

    // ---- P2: MFMA GEMM (512 x [128..144] x 128) + tanh + sig contraction ----
    {
      const int lane = tid & 63, wv = tid >> 6;
      const int col = lane & 15, qd = lane >> 4;
      const int mbase = wv * 64;       // each of 8 waves owns 64 batch rows
      short8 afr[4][4];                // A fragments [m-tile][k-block]
      #pragma unroll
      for (int m = 0; m < 4; ++m) {
        const int row = mbase + m * 16 + col;
        #pragma unroll
        for (int kb = 0; kb < 4; ++kb) {
          union { unsigned long long u[2]; short8 s; } cv;
          const size_t bi = (size_t)row * 32 + kb * 8 + qd * 2;
          cv.u[0] = LOADC(&H64[bi]);
          cv.u[1] = LOADC(&H64[bi + 1]);
          afr[m][kb] = cv.s;
        }
      }
      float kp[4][4];
      #pragma unroll
      for (int m = 0; m < 4; ++m)
        #pragma unroll
        for (int r = 0; r < 4; ++r) kp[m][r] = 0.0f;

      for (int nt = 0; nt < ntiles; ++nt) {
        const float bv = b3lds[nt * 16 + col];
        float4_ acc[4];
        #pragma unroll
        for (int m = 0; m < 4; ++m) { acc[m][0]=bv; acc[m][1]=bv; acc[m][2]=bv; acc[m][3]=bv; }
        #pragma unroll
        for (int kb = 0; kb < 4; ++kb) {
          const short8 bf = *(const short8*)(W3lds + (nt * 4 + kb) * 512 + lane * 8);
          acc[0] = __builtin_amdgcn_mfma_f32_16x16x32_bf16(afr[0][kb], bf, acc[0], 0, 0, 0);
          acc[1] = __builtin_amdgcn_mfma_f32_16x16x32_bf16(afr[1][kb], bf, acc[1], 0, 0, 0);
          acc[2] = __builtin_amdgcn_mfma_f32_16x16x32_bf16(afr[2][kb], bf, acc[2], 0, 0, 0);
          acc[3] = __builtin_amdgcn_mfma_f32_16x16x32_bf16(afr[3][kb], bf, acc[3], 0, 0, 0);
        }
        const int lrow = l0g + nt * 16 + col;
        #pragma unroll
        for (int m = 0; m < 4; ++m) {
          const float4_ s4 = *(const float4_*)(SGT + (size_t)lrow * 512 + mbase + m * 16 + qd * 4);
          #pragma unroll
          for (int r = 0; r < 4; ++r)
            kp[m][r] = fmaf(fast_tanh(acc[m][r]), s4[r], kp[m][r]);
        }
      }
      // reduce partial k over the 16 column-lanes of each quad
      #pragma unroll
      for (int m = 0; m < 4; ++m) {
        #pragma unroll
        for (int r = 0; r < 4; ++r) {
          float v = kp[m][r];
          v += __shfl_xor(v, 1);
          v += __shfl_xor(v, 2);
          v += __shfl_xor(v, 4);
          v += __shfl_xor(v, 8);
          kp[m][r] = v;
        }
      }
      if (col == 0) {
        #pragma unroll
        for (int m = 0; m < 4; ++m) {
          #pragma unroll
          for (int r = 0; r < 4; ++r) {
            const int b = mbase + m * 16 + qd * 4 + r;
            STOREC(&KP[((size_t)q * 512 + b) * 64 + h], kp[m][r]);
          }
        }
      }
    }
    gridbar(FLG, 2u * (unsigned)sg + 2u, g);
  }

  // ---------------- epilogue: final y, head, softmax ----------------
  if (tid < 128) {
    const int row = tid >> 6, hh = tid & 63;
    const int b = 2 * g + row;
    float s = LOADC(&KP[(size_t)(0 * 512 + b) * 64 + hh])
            + LOADC(&KP[(size_t)(1 * 512 + b) * 64 + hh])
            + LOADC(&KP[(size_t)(2 * 512 + b) * 64 + hh])
            + LOADC(&KP[(size_t)(3 * 512 + b) * 64 + hh]);
    float comb = 0.09646076681806523f  * kh[0][row][hh]
               + 0.01f                 * kh[1][row][hh]
               + 0.4798896504144996f   * kh[2][row][hh]
               + 1.379008574103742f    * kh[3][row][hh]
               + (-3.290069515436081f) * kh[4][row][hh]
               + 2.324710524099774f    * s;
    yLDS[row][hh] += dtv * comb;
  }
  __syncthreads();
  if (tid < 20) {
    const int row = tid / 10, c = tid % 10;
    float acc = l2b[c];
    const float* wr = l2w + c * 64;
    #pragma unroll
    for (int i2 = 0; i2 < 64; ++i2) acc = fmaf(yLDS[row][i2], wr[i2], acc);
    hbA[row][c] = acc;
  }
  __syncthreads();
  if (tid < 2) {
    const int row = tid;
    float mx = -1e30f;
    for (int c = 0; c < 10; ++c) mx = fmaxf(mx, hbA[row][c]);
    float ev[10], den = 0.0f;
    for (int c = 0; c < 10; ++c) { ev[c] = expf(hbA[row][c] - mx); den += ev[c]; }
    float rd = 1.0f / den;
    for (int c = 0; c < 10; ++c) out[(size_t)(2 * g + row) * 10 + c] = ev[c] * rd;
  }
}

extern "C" void kernel_launch(void* const* d_in, const int* in_sizes, int n_in,
                              void* d_out, int out_size, void* d_ws, size_t ws_size,
                              hipStream_t stream) {
  (void)in_sizes; (void)n_in; (void)out_size; (void)ws_size;
  const float* ts        = (const float*)d_in[0];
  const float* logsig    = (const float*)d_in[1];
  const float* x0        = (const float*)d_in[2];
  const float* intervals = (const float*)d_in[3];
  const float* w0        = (const float*)d_in[4];
  const float* b0        = (const float*)d_in[5];
  const float* w1        = (const float*)d_in[6];
  const float* b1        = (const float*)d_in[7];
  const float* w2        = (const float*)d_in[8];
  const float* b2        = (const float*)d_in[9];
  const float* w3        = (const float*)d_in[10];
  const float* b3        = (const float*)d_in[11];
  const float* l1w       = (const float*)d_in[12];
  const float* l1b       = (const float*)d_in[13];
  const float* l2w       = (const float*)d_in[14];
  const float* l2b       = (const float*)d_in[15];
  float* out = (float*)d_out;
  unsigned char* ws = (unsigned char*)d_ws;

  hipMemsetAsync(d_ws, 0, 1024, stream);  // zero arrival flags (ws is poisoned)

  void* args[] = { &ts, &logsig, &x0, &intervals, &w0, &b0, &w1, &b1,
                   &w2, &b2, &w3, &b3, &l1w, &l1b, &l2w, &l2b, &out, &ws };
  hipLaunchCooperativeKernel((void*)rde_kernel, dim3(NBLK), dim3(NTHR), args, 0, stream);
}

// Round 4
// 47438.562 us; speedup vs baseline: 1.2488x; 1.2488x over previous
//
#include <hip/hip_runtime.h>
#include <stdint.h>

#define NBLK 256
#define NTHR 512

typedef __attribute__((ext_vector_type(8))) short short8;
typedef __attribute__((ext_vector_type(4))) float float4_;

// workspace layout (bytes)
#define WS_BAR   0          // 10 words spaced 128B apart: 8 leaves, root, gen = 1536
#define WS_HDN   1536       // 512*128 ushort (bf16)   = 131072
#define WS_KP    132608     // 4*512*64 float          = 524288
#define WS_SIGT  656896     // 528*512 float           = 1081344
// total = 1738240 bytes

#define LOADC(p)    __hip_atomic_load((p),  __ATOMIC_RELAXED, __HIP_MEMORY_SCOPE_SYSTEM)
#define STOREC(p,v) __hip_atomic_store((p), (v), __ATOMIC_RELAXED, __HIP_MEMORY_SCOPE_SYSTEM)

__device__ __forceinline__ unsigned short f2bf(float x) {
  union { float f; unsigned u; } v; v.f = x;
  return (unsigned short)((v.u + 0x7fffu + ((v.u >> 16) & 1u)) >> 16);
}

__device__ __forceinline__ float fast_exp(float x) {  // e^x ; saturates cleanly
  return __builtin_amdgcn_exp2f(x * 1.4426950408889634f);
}

__device__ __forceinline__ float fast_tanh(float x) {
  // e^(2x): overflow->inf => rcp->0 => tanh=1 ; underflow->0 => tanh=-1.
  float e = __builtin_amdgcn_exp2f(x * 2.8853900817779268f);
  return fmaf(-2.0f, __builtin_amdgcn_rcpf(e + 1.0f), 1.0f);
}

__device__ __forceinline__ float fast_silu(float x) {
  float e = fast_exp(-x);
  return x * __builtin_amdgcn_rcpf(1.0f + e);
}

// Hierarchical-arrival / single-word-broadcast grid barrier.
// Arrival: 8 leaf counters (one cacheline each, g&7) absorb <=32 same-line RMWs
// in parallel; last of each leaf RMWs the root; last leaf stores gen=bn.
// Detection: every block's tid0 polls the single gen word (R2's proven cheap path).
// Counters are monotone (leaf target 32*bn, root 8*bn) -> no reset, no ABA.
// __syncthreads() at entry: every wave drains vmcnt(0) before s_barrier, so all
// system-scope data stores are at the coherence point before any arrival RMW.
__device__ __forceinline__ void gridbar(unsigned* bar, int g, unsigned bn) {
  __syncthreads();
  if (threadIdx.x == 0) {
    unsigned* leaf = bar + 32 * (g & 7);
    unsigned* root = bar + 32 * 8;
    unsigned* gen  = bar + 32 * 9;
    unsigned a = __hip_atomic_fetch_add(leaf, 1u, __ATOMIC_RELAXED, __HIP_MEMORY_SCOPE_SYSTEM);
    if (a == 32u * bn - 1u) {
      unsigned r = __hip_atomic_fetch_add(root, 1u, __ATOMIC_RELAXED, __HIP_MEMORY_SCOPE_SYSTEM);
      if (r == 8u * bn - 1u) {
        STOREC(gen, bn);
      }
    }
    while (LOADC(gen) < bn)
      __builtin_amdgcn_s_sleep(1);
  }
  __syncthreads();
}

__global__ void __launch_bounds__(NTHR, 2)
rde_kernel(const float* __restrict__ ts, const float* __restrict__ logsig,
           const float* __restrict__ x0, const float* __restrict__ intervals,
           const float* __restrict__ w0, const float* __restrict__ b0,
           const float* __restrict__ w1, const float* __restrict__ b1,
           const float* __restrict__ w2, const float* __restrict__ b2,
           const float* __restrict__ w3, const float* __restrict__ b3,
           const float* __restrict__ l1w, const float* __restrict__ l1b,
           const float* __restrict__ l2w, const float* __restrict__ l2b,
           float* out, unsigned char* ws) {
  const int tid = threadIdx.x;
  const int g   = blockIdx.x;
  const int h   = g >> 2;          // owned output-head (0..63)
  const int q   = g & 3;           // quarter of the 528 l-range
  const int ntiles = (q == 3) ? 9 : 8;   // 16-wide n-tiles (33 per h total)
  const int l0g = q << 7;          // l offset within h's 528

  unsigned long long* H64 = (unsigned long long*)(ws + WS_HDN);
  float* KP  = (float*)(ws + WS_KP);
  float* SGT = (float*)(ws + WS_SIGT);
  unsigned* BAR = (unsigned*)(ws + WS_BAR);

  __shared__ __attribute__((aligned(16))) unsigned short W3lds[18432]; // 36.9 KB
  __shared__ float b3lds[144];
  __shared__ float intv[64];
  __shared__ float yLDS[2][64];
  __shared__ float kh[6][2][64];
  __shared__ float yst[2][64];
  __shared__ float hbA[2][128];
  __shared__ float hbB[2][128];
  __shared__ __attribute__((aligned(8))) unsigned short hdnS[2][128];
  __shared__ float tsc[16][513];   // transpose scratch (32.8 KB)
  __shared__ int   sidx;

  // ---------------- init ----------------
  if (tid < 64) intv[tid] = intervals[tid];
  {
    const int tot = ntiles * 16 * 128;
    for (int e = tid; e < tot; e += NTHR) {
      int k  = e & 127;
      int nc = e >> 7;
      float v = w3[(size_t)(h * 528 + l0g + nc) * 128 + k];
      int col = nc & 15, nt = nc >> 4;
      int kb = k >> 5, qd = (k >> 3) & 3, j = k & 7;
      // layout: lane reads contiguous 16B at (nt*4+kb)*512 + lane*8
      W3lds[(nt * 4 + kb) * 512 + qd * 128 + col * 8 + j] = f2bf(v);
    }
    for (int e = tid; e < ntiles * 16; e += NTHR)
      b3lds[e] = b3[h * 528 + l0g + e];
  }
  if (tid < 128) {  // y0 = x0 @ l1_w.T + l1_b for own 2 rows
    int row = tid >> 6, hh = tid & 63;
    float acc = l1b[hh];
    const float* xr = x0 + (size_t)(2 * g + row) * 32;
    const float* wr = l1w + hh * 32;
    #pragma unroll
    for (int d = 0; d < 32; ++d) acc = fmaf(xr[d], wr[d], acc);
    yLDS[row][hh] = acc;
  }
  const float t0v = ts[0];
  const float dtv = (ts[128] - t0v) * (1.0f / 256.0f);
  int last_idx = -1;
  __syncthreads();

  // ---------------- 1536 sequential RK stages ----------------
  for (int sg = 0; sg < 1536; ++sg) {
    const int s_in  = sg % 6;
    const int stepi = sg / 6;

    // ---- P1: consume k of previous stage, RK combine, MLP -> hdn ----
    if (tid < 128) {
      const int row = tid >> 6, hh = tid & 63;
      if (sg > 0) {
        const int b = 2 * g + row;
        const int pi = (s_in == 0) ? 5 : (s_in - 1);
        float s = LOADC(&KP[(size_t)(0 * 512 + b) * 64 + hh])
                + LOADC(&KP[(size_t)(1 * 512 + b) * 64 + hh])
                + LOADC(&KP[(size_t)(2 * 512 + b) * 64 + hh])
                + LOADC(&KP[(size_t)(3 * 512 + b) * 64 + hh]);
        kh[pi][row][hh] = s;
      }
      float yv = yLDS[row][hh];
      if (s_in == 0) {
        if (sg > 0) {
          float comb = 0.09646076681806523f  * kh[0][row][hh]
                     + 0.01f                 * kh[1][row][hh]
                     + 0.4798896504144996f   * kh[2][row][hh]
                     + 1.379008574103742f    * kh[3][row][hh]
                     + (-3.290069515436081f) * kh[4][row][hh]
                     + 2.324710524099774f    * kh[5][row][hh];
          yv += dtv * comb;
          yLDS[row][hh] = yv;
        }
        yst[row][hh] = yv;
      } else {
        float comb;
        switch (s_in) {
          case 1: comb = 0.161f * kh[0][row][hh]; break;
          case 2: comb = -0.008480655492356989f * kh[0][row][hh]
                        + 0.335480655492357f    * kh[1][row][hh]; break;
          case 3: comb = 2.8971530571054935f  * kh[0][row][hh]
                        - 6.359448489975075f  * kh[1][row][hh]
                        + 4.3622954328695815f * kh[2][row][hh]; break;
          case 4: comb = 5.325864828439257f    * kh[0][row][hh]
                        - 11.748883564062828f  * kh[1][row][hh]
                        + 7.4955393428898365f  * kh[2][row][hh]
                        - 0.09249506636175525f * kh[3][row][hh]; break;
          default: comb = 5.86145544294642f      * kh[0][row][hh]
                        - 12.92096931784711f     * kh[1][row][hh]
                        + 8.159367898576159f     * kh[2][row][hh]
                        - 0.071584973281401f     * kh[3][row][hh]
                        - 0.028269050394068383f  * kh[4][row][hh]; break;
        }
        yst[row][hh] = yv + dtv * comb;
      }
    }
    // stage time + searchsorted idx (wave0 ballot)
    {
      float t_s = __fadd_rn(t0v, __fmul_rn((float)stepi, dtv));
      if (s_in != 0) {
        float c = (s_in == 1) ? 0.161f : (s_in == 2) ? 0.327f : (s_in == 3) ? 0.9f
                : (s_in == 4) ? 0.9800255409045097f : 1.0f;
        t_s = __fadd_rn(t_s, __fmul_rn(c, dtv));
      }
      if (tid < 64) {
        unsigned long long m = __ballot(intv[tid] < t_s);
        if (tid == 0) sidx = (int)__popcll(m);
      }
    }
    __syncthreads();
    const int idx = sidx;
    // idx is monotone non-decreasing over stages -> <=65 rebuilds of sigT
    const bool rebuild = (idx != last_idx);
    if (rebuild) {
      last_idx = idx;
      if (g < 33) {  // blocks 0..32 transpose one 16-wide l-stripe each
        const int l0t = g * 16;
        #pragma unroll 1
        for (int it = 0; it < 16; ++it) {
          int li = tid & 15, b = (tid >> 4) + 32 * it;
          tsc[li][b] = logsig[((size_t)b * 65 + idx) * 529 + 1 + l0t + li];
        }
        __syncthreads();
        #pragma unroll 1
        for (int it = 0; it < 16; ++it) {
          int li = tid >> 5, b = (tid & 31) + 32 * it;
          STOREC(&SGT[(size_t)(l0t + li) * 512 + b], tsc[li][b]);
        }
      }
    }
    // MLP (2 rows, 256 threads): silu(y@w0^T) -> silu(@w1^T) -> silu(@w2^T) -> hdn bf16
    if (tid < 256) {
      const int row = tid >> 7, j = tid & 127;
      float acc = b0[j];
      const float4_* wr = (const float4_*)(w0 + (size_t)j * 64);
      #pragma unroll
      for (int i4 = 0; i4 < 16; ++i4) {
        float4_ wv = wr[i4];
        acc = fmaf(yst[row][4*i4+0], wv[0], acc);
        acc = fmaf(yst[row][4*i4+1], wv[1], acc);
        acc = fmaf(yst[row][4*i4+2], wv[2], acc);
        acc = fmaf(yst[row][4*i4+3], wv[3], acc);
      }
      hbA[row][j] = fast_silu(acc);
    }
    __syncthreads();
    if (tid < 256) {
      const int row = tid >> 7, j = tid & 127;
      float acc = b1[j];
      const float4_* wr = (const float4_*)(w1 + (size_t)j * 128);
      #pragma unroll
      for (int i4 = 0; i4 < 32; ++i4) {
        float4_ wv = wr[i4];
        acc = fmaf(hbA[row][4*i4+0], wv[0], acc);
        acc = fmaf(hbA[row][4*i4+1], wv[1], acc);
        acc = fmaf(hbA[row][4*i4+2], wv[2], acc);
        acc = fmaf(hbA[row][4*i4+3], wv[3], acc);
      }
      hbB[row][j] = fast_silu(acc);
    }
    __syncthreads();
    if (tid < 256) {
      const int row = tid >> 7, j = tid & 127;
      float acc = b2[j];
      const float4_* wr = (const float4_*)(w2 + (size_t)j * 128);
      #pragma unroll
      for (int i4 = 0; i4 < 32; ++i4) {
        float4_ wv = wr[i4];
        acc = fmaf(hbB[row][4*i4+0], wv[0], acc);
        acc = fmaf(hbB[row][4*i4+1], wv[1], acc);
        acc = fmaf(hbB[row][4*i4+2], wv[2], acc);
        acc = fmaf(hbB[row][4*i4+3], wv[3], acc);
      }
      hdnS[row][j] = f2bf(fast_silu(acc));
    }
    __syncthreads();
    if (tid < 64) {  // pack 2 rows (512 B) as 64 coherent 8B stores
      const unsigned long long* s64 = (const unsigned long long*)&hdnS[0][0];
      STOREC(&H64[(size_t)g * 64 + tid], s64[tid]);
    }
    gridbar(BAR, g, 2u * (unsigned)sg + 1u);
    if (rebuild) __builtin_amdgcn_fence(__ATOMIC_ACQUIRE, "agent"); // invalidate stale SGT lines (rare)

    // ---- P2: MFMA GEMM (512 x [128..144] x 128) + tanh + sig contraction ----
    {
      const int lane = tid & 63, wv = tid >> 6;
      const int col = lane & 15, qd = lane >> 4;
      const int mbase = wv * 64;       // each of 8 waves owns 64 batch rows
      short8 afr[4][4];                // A fragments [m-tile][k-block]
      #pragma unroll
      for (int m = 0; m < 4; ++m) {
        const int row = mbase + m * 16 + col;
        #pragma unroll
        for (int kb = 0; kb < 4; ++kb) {
          union { unsigned long long u[2]; short8 s; } cv;
          const size_t bi = (size_t)row * 32 + kb * 8 + qd * 2;
          cv.u[0] = LOADC(&H64[bi]);
          cv.u[1] = LOADC(&H64[bi + 1]);
          afr[m][kb] = cv.s;
        }
      }
      float kp[4][4];
      #pragma unroll
      for (int m = 0; m < 4; ++m)
        #pragma unroll
        for (int r = 0; r < 4; ++r) kp[m][r] = 0.0f;

      for (int nt = 0; nt < ntiles; ++nt) {
        const float bv = b3lds[nt * 16 + col];
        float4_ acc[4];
        #pragma unroll
        for (int m = 0; m < 4; ++m) { acc[m][0]=bv; acc[m][1]=bv; acc[m][2]=bv; acc[m][3]=bv; }
        #pragma unroll
        for (int kb = 0; kb < 4; ++kb) {
          const short8 bf = *(const short8*)(W3lds + (nt * 4 + kb) * 512 + lane * 8);
          acc[0] = __builtin_amdgcn_mfma_f32_16x16x32_bf16(afr[0][kb], bf, acc[0], 0, 0, 0);
          acc[1] = __builtin_amdgcn_mfma_f32_16x16x32_bf16(afr[1][kb], bf, acc[1], 0, 0, 0);
          acc[2] = __builtin_amdgcn_mfma_f32_16x16x32_bf16(afr[2][kb], bf, acc[2], 0, 0, 0);
          acc[3] = __builtin_amdgcn_mfma_f32_16x16x32_bf16(afr[3][kb], bf, acc[3], 0, 0, 0);
        }
        const int lrow = l0g + nt * 16 + col;
        #pragma unroll
        for (int m = 0; m < 4; ++m) {
          const float4_ s4 = *(const float4_*)(SGT + (size_t)lrow * 512 + mbase + m * 16 + qd * 4);
          #pragma unroll
          for (int r = 0; r < 4; ++r)
            kp[m][r] = fmaf(fast_tanh(acc[m][r]), s4[r], kp[m][r]);
        }
      }
      // reduce partial k over the 16 column-lanes of each quad
      #pragma unroll
      for (int m = 0; m < 4; ++m) {
        #pragma unroll
        for (int r = 0; r < 4; ++r) {
          float v = kp[m][r];
          v += __shfl_xor(v, 1);
          v += __shfl_xor(v, 2);
          v += __shfl_xor(v, 4);
          v += __shfl_xor(v, 8);
          kp[m][r] = v;
        }
      }
      if (col == 0) {
        #pragma unroll
        for (int m = 0; m < 4; ++m) {
          #pragma unroll
          for (int r = 0; r < 4; ++r) {
            const int b = mbase + m * 16 + qd * 4 + r;
            STOREC(&KP[((size_t)q * 512 + b) * 64 + h], kp[m][r]);
          }
        }
      }
    }
    gridbar(BAR, g, 2u * (unsigned)sg + 2u);
  }

  // ---------------- epilogue: final y, head, softmax ----------------
  if (tid < 128) {
    const int row = tid >> 6, hh = tid & 63;
    const int b = 2 * g + row;
    float s = LOADC(&KP[(size_t)(0 * 512 + b) * 64 + hh])
            + LOADC(&KP[(size_t)(1 * 512 + b) * 64 + hh])
            + LOADC(&KP[(size_t)(2 * 512 + b) * 64 + hh])
            + LOADC(&KP[(size_t)(3 * 512 + b) * 64 + hh]);
    float comb = 0.09646076681806523f  * kh[0][row][hh]
               + 0.01f                 * kh[1][row][hh]
               + 0.4798896504144996f   * kh[2][row][hh]
               + 1.379008574103742f    * kh[3][row][hh]
               + (-3.290069515436081f) * kh[4][row][hh]
               + 2.324710524099774f    * s;
    yLDS[row][hh] += dtv * comb;
  }
  __syncthreads();
  if (tid < 20) {
    const int row = tid / 10, c = tid % 10;
    float acc = l2b[c];
    const float* wr = l2w + c * 64;
    #pragma unroll
    for (int i2 = 0; i2 < 64; ++i2) acc = fmaf(yLDS[row][i2], wr[i2], acc);
    hbA[row][c] = acc;
  }
  __syncthreads();
  if (tid < 2) {
    const int row = tid;
    float mx = -1e30f;
    for (int c = 0; c < 10; ++c) mx = fmaxf(mx, hbA[row][c]);
    float ev[10], den = 0.0f;
    for (int c = 0; c < 10; ++c) { ev[c] = expf(hbA[row][c] - mx); den += ev[c]; }
    float rd = 1.0f / den;
    for (int c = 0; c < 10; ++c) out[(size_t)(2 * g + row) * 10 + c] = ev[c] * rd;
  }
}

extern "C" void kernel_launch(void* const* d_in, const int* in_sizes, int n_in,
                              void* d_out, int out_size, void* d_ws, size_t ws_size,
                              hipStream_t stream) {
  (void)in_sizes; (void)n_in; (void)out_size; (void)ws_size;
  const float* ts        = (const float*)d_in[0];
  const float* logsig    = (const float*)d_in[1];
  const float* x0        = (const float*)d_in[2];
  const float* intervals = (const float*)d_in[3];
  const float* w0        = (const float*)d_in[4];
  const float* b0        = (const float*)d_in[5];
  const float* w1        = (const float*)d_in[6];
  const float* b1        = (const float*)d_in[7];
  const float* w2        = (const float*)d_in[8];
  const float* b2        = (const float*)d_in[9];
  const float* w3        = (const float*)d_in[10];
  const float* b3        = (const float*)d_in[11];
  const float* l1w       = (const float*)d_in[12];
  const float* l1b       = (const float*)d_in[13];
  const float* l2w       = (const float*)d_in[14];
  const float* l2b       = (const float*)d_in[15];
  float* out = (float*)d_out;
  unsigned char* ws = (unsigned char*)d_ws;

  hipMemsetAsync(d_ws, 0, 1536, stream);  // zero barrier counters (ws is poisoned)

  void* args[] = { &ts, &logsig, &x0, &intervals, &w0, &b0, &w1, &b1,
                   &w2, &b2, &w3, &b3, &l1w, &l1b, &l2w, &l2b, &out, &ws };
  hipLaunchCooperativeKernel((void*)rde_kernel, dim3(NBLK), dim3(NTHR), args, 0, stream);
}